// Round 1
// baseline (3513.729 us; speedup 1.0000x reference)
//
#include <hip/hip_runtime.h>

// Persistent pipelined 2-layer LSTM for MI355X (gfx950).
// R10: R9 + flat single-hop barrier (no master/release tree).
//  - 256 WGs x 512 threads; blocks 0..127 layer 0, 128..255 layer 1.
//  - waves: ntile = wave>>2 (batch 16-tile), r = wave&3:
//      r 0,1 -> h-waves (K-halves of the recurrent part, both M-tiles;
//               r1 runs the epilogue), r 2,3 -> x-waves (K-halves of x-part).
//  - window w: h-waves run step t=w-1; x-waves compute x-partials for step w
//    into LDS xbuf (double buffer) AFTER the mid sync -> hidden under the poll.
//  - per-LAYER barrier (R10, flat): arrives from the 2 epilogue waves
//    (LDS-combined to one agent RMW) onto stripe (lidx&15); EVERY WG's wave 0
//    polls all 16 stripes directly with lanes 0..15 (target e*8). Cross-layer
//    edge: layer-1 wave-0 lanes 32..47 poll layer-0's 16 stripes against
//    (e+2)*8 (stripe value s*8 => L0 epoch s done => O0 slot s-2 published).
//    This removes the master-detect + release-store + release-poll hops
//    (2 serialized LLC round trips) from the window critical path.
//  - h publish sc1 (write-through to LLC); consume plain-cached (write-once
//    slots + launch-boundary L2 invalidate => never stale).
// Bounded sleep-free spins + abort flag: failure = fast reported absmax.

typedef unsigned short ushort_t;
typedef unsigned long long u64_t;
typedef __attribute__((ext_vector_type(8))) short short8;   // 8 bf16 MFMA operand
typedef __attribute__((ext_vector_type(4))) float f32x4;

#define NWG       256
#define NTHREADS  512
#define SEQ       512
#define HSLOT     32768        // 32*1024 elements per time slot
#define FULLSLOTS 513
#define LBASE     4096         // per-layer counter region, u32 units (16 KB)
#define ABORT_U32 8128         // one global abort word
#define CNT_BYTES 32768
#define POLL_MAX  20000        // then abort -> fast wrong-answer, not a hang

__device__ __forceinline__ ushort_t f2bf(float f) {
  unsigned u = __builtin_bit_cast(unsigned, f);
  u += 0x7FFFu + ((u >> 16) & 1u);      // round-to-nearest-even
  return (ushort_t)(u >> 16);
}

__device__ __forceinline__ short8 pack_bf8(f32x4 a, f32x4 b) {
  short8 r;
  r[0] = (short)f2bf(a[0]); r[1] = (short)f2bf(a[1]);
  r[2] = (short)f2bf(a[2]); r[3] = (short)f2bf(a[3]);
  r[4] = (short)f2bf(b[0]); r[5] = (short)f2bf(b[1]);
  r[6] = (short)f2bf(b[2]); r[7] = (short)f2bf(b[3]);
  return r;
}

__device__ __forceinline__ float sigm(float x) { return 1.0f / (1.0f + __expf(-x)); }
__device__ __forceinline__ float fast_tanh(float x) {
  x = fminf(fmaxf(x, -15.f), 15.f);
  float e = __expf(-2.0f * x);
  return (1.0f - e) / (1.0f + e);
}

// Per-layer barrier epoch, flat single-hop (R10).
// Arrive: epilogue waves (1,5) lane0 LDS-combine; the 2nd does one agent-scope
// RMW on stripe (lidx&15).  Wave 0 polls:
//   lanes 0..15  : own layer's 16 stripes, target e*8
//   lanes 32..47 : other layer's 16 stripes, target progEpoch*8 (0 = skip)
// All conditions polled in ONE sleep-free loop (parallel lanes, independent
// per-lane exit).
__device__ __forceinline__ void bar_epoch(unsigned* cntOwn, unsigned* cntOther,
                                          unsigned* abortp, unsigned* hcount,
                                          unsigned e, int lidx,
                                          unsigned progEpoch) {
  const int wave = threadIdx.x >> 6;
  const int lane = threadIdx.x & 63;

  if ((wave == 1 || wave == 5) && lane == 0) {
    unsigned old = atomicAdd(hcount, 1u);          // LDS combine, monotonic
    if (old & 1u)
      __hip_atomic_fetch_add(cntOwn + (lidx & 15) * 64, 1u,
                             __ATOMIC_RELAXED, __HIP_MEMORY_SCOPE_AGENT);
  }

  if (wave == 0) {
    const unsigned* addr = nullptr;
    unsigned tgt = 0;
    if (lane < 16) {
      addr = cntOwn + lane * 64;   tgt = e * 8u;
    } else if (lane >= 32 && lane < 48 && progEpoch) {
      addr = cntOther + (lane - 32) * 64;  tgt = progEpoch * 8u;
    }
    if (addr) {
      for (int it = 0;; ++it) {
        if (__hip_atomic_load(addr, __ATOMIC_RELAXED, __HIP_MEMORY_SCOPE_AGENT) >= tgt) break;
        if ((it & 31) == 31 &&
            __hip_atomic_load(abortp, __ATOMIC_RELAXED, __HIP_MEMORY_SCOPE_AGENT) != 0) break;
        if (it >= POLL_MAX) {
          __hip_atomic_store(abortp, 1u, __ATOMIC_RELAXED, __HIP_MEMORY_SCOPE_AGENT);
          break;
        }
      }
    }
  }
  __syncthreads();   // window boundary
}

// One layer: 513 windows (w=0..512), barrier epoch e=w+2 after each.
//   window w: h-waves run step t=w-1 (w>=1); x-waves compute x-part of step
//   s=w (s<SEQ) into xbuf[s&1] AFTER the mid sync (hidden under the poll).
// MFMA 16x16x32: A row m: gate=m&3, unit=ub+mt*4+(m>>2).
// C/D: col = lane&15 (=batch), row = (lane>>4)*4 + reg -> reg = gate.
template<int KX, bool XFP32, bool ISL1>
__device__ __forceinline__ void run_layer(
    const void* xsrc, long x_step, long x_bstride,
    const ushort_t* __restrict__ hbuf, ushort_t* __restrict__ hbuf_w,
    const float* __restrict__ W, int ldw,
    const float* __restrict__ bias,
    float* __restrict__ out, int out_h_off, int out_c_off, int write_last,
    float* xbuf, float* red, unsigned* hcount,
    unsigned* cntOwn, unsigned* cntOther, unsigned* abortp,
    int lidx, int ub)
{
  constexpr int XCH = (KX / 2) / 32;                // x chunks per x-wave
  const int lane  = threadIdx.x & 63;
  const int wave  = threadIdx.x >> 6;               // 0..7
  const int ntile = wave >> 2;                      // 0,1
  const int r     = wave & 3;                       // 0,1: h-waves; 2,3: x-waves
  const bool isH  = r < 2;
  const int sub   = r & 1;
  const int wrow  = lane & 15;
  const int koff  = (lane >> 4) * 8;                // frag k offset (elements)
  const int bb    = ntile * 16 + (lane & 15);       // batch

  // ---- pin weight fragments (bf16), 2 M-tiles per wave ----
  const int kbase = isH ? (KX + sub * 512) : ((r - 2) * (KX / 2));
  const int mych  = isH ? 16 : XCH;
  short8 wreg[2][16];
  #pragma unroll
  for (int mt = 0; mt < 2; ++mt) {
    const int grow = (wrow & 3) * 1024 + ub + mt * 4 + (wrow >> 2);
    const float* ws = W + (long)grow * ldw + kbase + koff;
    #pragma unroll
    for (int ch = 0; ch < 16; ++ch) {
      if (ch < mych) {
        f32x4 v0 = *(const f32x4*)(ws + ch * 32);
        f32x4 v1 = *(const f32x4*)(ws + ch * 32 + 4);
        wreg[mt][ch] = pack_bf8(v0, v1);
      }
    }
  }

  const int u0 = ub + (lane >> 4);
  float bI[2], bF[2], bG[2], bO[2], c[2] = {0.f, 0.f};
  #pragma unroll
  for (int mt = 0; mt < 2; ++mt) {
    const int u = u0 + mt * 4;
    bI[mt] = bias[u];        bF[mt] = bias[1024 + u];
    bG[mt] = bias[2048 + u]; bO[mt] = bias[3072 + u];
  }

  for (int w = 0; w <= SEQ; ++w) {
    const int t = w - 1;
    f32x4 acc[2] = {{0.f,0.f,0.f,0.f},{0.f,0.f,0.f,0.f}};

    if (isH && w >= 1) {
      // h K-half: 16x16B loads in one flight, 32 MFMAs (2 M-tiles)
      const ushort_t* bp = hbuf + (long)t * HSLOT + (long)bb * 1024 + sub * 512 + koff;
      short8 hv[16];
      #pragma unroll
      for (int ch = 0; ch < 16; ++ch) hv[ch] = *(const short8*)(bp + ch * 32);
      #pragma unroll
      for (int ch = 0; ch < 16; ++ch) {
        acc[0] = __builtin_amdgcn_mfma_f32_16x16x32_bf16(wreg[0][ch], hv[ch], acc[0], 0, 0, 0);
        acc[1] = __builtin_amdgcn_mfma_f32_16x16x32_bf16(wreg[1][ch], hv[ch], acc[1], 0, 0, 0);
      }
      if (sub == 0) {
        #pragma unroll
        for (int mt = 0; mt < 2; ++mt)
          *(f32x4*)&red[((ntile * 2 + mt) * 64 + lane) * 4] = acc[mt];
      }
    }

    __syncthreads();   // A: red ready; xbuf[t&1] from window t-1 already ready

    if (isH && sub == 1 && w >= 1) {
      // ---- epilogue (both M-tiles) ----
      u64_t pk[2]; float hh[2];
      #pragma unroll
      for (int mt = 0; mt < 2; ++mt) {
        f32x4 a = acc[mt];
        a += *(const f32x4*)&red[((ntile * 2 + mt) * 64 + lane) * 4];
        a += *(const f32x4*)&xbuf[(((((t & 1) * 2 + ntile) * 2 + 0) * 2 + mt) * 64 + lane) * 4];
        a += *(const f32x4*)&xbuf[(((((t & 1) * 2 + ntile) * 2 + 1) * 2 + mt) * 64 + lane) * 4];
        float pi = a[0] + bI[mt], pf = a[1] + bF[mt];
        float pg = a[2] + bG[mt], po = a[3] + bO[mt];
        float ig = sigm(pi), fg = sigm(pf), gg = fast_tanh(pg), og = sigm(po);
        c[mt] = fg * c[mt] + ig * gg;
        float h = og * fast_tanh(c[mt]);
        hh[mt] = h;
        unsigned v  = f2bf(h);
        unsigned v1 = __shfl((int)v, (lane & 15) + 16);
        unsigned v2 = __shfl((int)v, (lane & 15) + 32);
        unsigned v3 = __shfl((int)v, (lane & 15) + 48);
        pk[mt] = (u64_t)(v & 0xFFFFu) | ((u64_t)(v1 & 0xFFFFu) << 16)
               | ((u64_t)(v2 & 0xFFFFu) << 32) | ((u64_t)(v3 & 0xFFFFu) << 48);
      }
      if (t == SEQ - 1) {
        #pragma unroll
        for (int mt = 0; mt < 2; ++mt) {
          const int u = u0 + mt * 4;
          out[out_h_off + bb * 1024 + u] = hh[mt];
          out[out_c_off + bb * 1024 + u] = c[mt];
          if (write_last) out[bb * 1024 + u] = hh[mt];
        }
      }
      if (lane < 16) {
        u64_t* dst = (u64_t*)(hbuf_w + (long)(t + 1) * HSLOT + (long)bb * 1024 + ub);
        __hip_atomic_store(dst,     pk[0], __ATOMIC_RELAXED, __HIP_MEMORY_SCOPE_AGENT);
        __hip_atomic_store(dst + 1, pk[1], __ATOMIC_RELAXED, __HIP_MEMORY_SCOPE_AGENT);
      }
      asm volatile("s_waitcnt vmcnt(0)" ::: "memory");   // drain publish
    }

    if (!isH && w < SEQ) {
      // ---- x-prefetch for step s=w (off critical path, hidden under poll) ----
      const int s = w;
      f32x4 xa[2] = {{0.f,0.f,0.f,0.f},{0.f,0.f,0.f,0.f}};
      if constexpr (XFP32) {
        const float* bp = (const float*)xsrc + (long)s * x_step
                          + (long)bb * x_bstride + kbase + koff;
        f32x4 xv[2 * XCH];
        #pragma unroll
        for (int ch = 0; ch < XCH; ++ch) {
          xv[2*ch]   = *(const f32x4*)(bp + ch * 32);
          xv[2*ch+1] = *(const f32x4*)(bp + ch * 32 + 4);
        }
        #pragma unroll
        for (int ch = 0; ch < XCH; ++ch) {
          short8 bf = pack_bf8(xv[2*ch], xv[2*ch+1]);
          xa[0] = __builtin_amdgcn_mfma_f32_16x16x32_bf16(wreg[0][ch], bf, xa[0], 0, 0, 0);
          xa[1] = __builtin_amdgcn_mfma_f32_16x16x32_bf16(wreg[1][ch], bf, xa[1], 0, 0, 0);
        }
      } else {
        const ushort_t* bp = (const ushort_t*)xsrc + (long)s * x_step
                             + (long)bb * x_bstride + kbase + koff;
        short8 xv[16];
        #pragma unroll
        for (int ch = 0; ch < 16; ++ch) xv[ch] = *(const short8*)(bp + ch * 32);
        #pragma unroll
        for (int ch = 0; ch < 16; ++ch) {
          xa[0] = __builtin_amdgcn_mfma_f32_16x16x32_bf16(wreg[0][ch], xv[ch], xa[0], 0, 0, 0);
          xa[1] = __builtin_amdgcn_mfma_f32_16x16x32_bf16(wreg[1][ch], xv[ch], xa[1], 0, 0, 0);
        }
      }
      #pragma unroll
      for (int mt = 0; mt < 2; ++mt)
        *(f32x4*)&xbuf[(((((s & 1) * 2 + ntile) * 2 + (r - 2)) * 2 + mt) * 64 + lane) * 4] = xa[mt];
    }

    // barrier epoch e = w+2; gates window w+1 (needs O0 slot w+2 for L1 x)
    const unsigned e = (unsigned)(w + 2);
    const unsigned pt = (ISL1 && e <= 512u) ? (e + 2u) : 0u;
    bar_epoch(cntOwn, cntOther, abortp, hcount, e, lidx, pt);
  }
}

__global__ __launch_bounds__(NTHREADS, 2)
void lstm_persistent(const float* __restrict__ x,  const float* __restrict__ W0,
                     const float* __restrict__ b0, const float* __restrict__ W1,
                     const float* __restrict__ b1, float* __restrict__ out,
                     unsigned* cnt, ushort_t* O0, ushort_t* H1)
{
  __shared__ float    xbuf[4096];   // [buf2][ntile2][xsub2][mt2][64][4] = 16 KB
  __shared__ float    red[1024];    // [ntile2][mt2][64][4] = 4 KB
  __shared__ unsigned hcount;
  const int  role = (int)(blockIdx.x >> 7);      // 0: layer0, 1: layer1
  const int  lidx = (int)(blockIdx.x & 127);
  const int  ub   = lidx * 8;
  unsigned* cntOwn  = cnt + role * LBASE;
  unsigned* cntOther= cnt + (1 - role) * LBASE;
  unsigned* abortp  = cnt + ABORT_U32;

  if (threadIdx.x == 0) hcount = 0;

  // zero own slice of slot 0 (this WG's publish region), device-visible (sc1)
  ushort_t* hb = role ? H1 : O0;
  if (threadIdx.x < 128) {
    int b = threadIdx.x >> 2, p = threadIdx.x & 3;
    __hip_atomic_store((unsigned*)hb + (long)b * 512 + (ub >> 1) + p, 0u,
                       __ATOMIC_RELAXED, __HIP_MEMORY_SCOPE_AGENT);
  }
  asm volatile("s_waitcnt vmcnt(0)" ::: "memory");
  __syncthreads();

  // init barrier (epoch 1); gates window 0 (L1 window 0 x needs O0 slot 1 ->
  // L0 epoch >= 3 = e+2)
  bar_epoch(cntOwn, cntOther, abortp, &hcount, 1u, lidx, role ? 3u : 0u);

  if (role == 0) {
    run_layer<512, true, false>(x, 512, 262144,
                                O0, O0, W0, 1536, b0,
                                out, 32768, 98304, 0,
                                xbuf, red, &hcount, cntOwn, cntOther, abortp,
                                lidx, ub);
  } else {
    // L1 x source: O0 shifted by one slot (window-w x reads O0 slot w+1)
    run_layer<1024, false, true>((const void*)(O0 + HSLOT), HSLOT, 1024,
                                 H1, H1, W1, 2048, b1,
                                 out, 65536, 131072, 1,
                                 xbuf, red, &hcount, cntOwn, cntOther, abortp,
                                 lidx, ub);
  }
}

extern "C" void kernel_launch(void* const* d_in, const int* in_sizes, int n_in,
                              void* d_out, int out_size, void* d_ws, size_t ws_size,
                              hipStream_t stream) {
  (void)in_sizes; (void)n_in; (void)out_size;

  const float* x  = (const float*)d_in[0];
  const float* W0 = (const float*)d_in[1];
  const float* b0 = (const float*)d_in[2];
  const float* W1 = (const float*)d_in[3];
  const float* b1 = (const float*)d_in[4];
  float* out = (float*)d_out;

  // workspace:
  //   [0, 32K)            2 per-layer counter regions (16 stripes, 256B apart)
  //                       + abort word
  //   [32K, +513*64KB)    O0: layer-0 h slots (write-once)
  //   [.., +513*64KB)     H1: layer-1 h slots (write-once)
  const size_t hb_bytes = (size_t)FULLSLOTS * HSLOT * sizeof(ushort_t);
  const size_t need     = CNT_BYTES + 2 * hb_bytes;
  if (ws_size < need) return;  // wrong answer -> absmax signal, not a hang

  unsigned* cnt = (unsigned*)d_ws;
  ushort_t* O0  = (ushort_t*)((char*)d_ws + CNT_BYTES);
  ushort_t* H1  = O0 + (size_t)FULLSLOTS * HSLOT;

  hipMemsetAsync(d_ws, 0, CNT_BYTES, stream);

  lstm_persistent<<<dim3(NWG), dim3(NTHREADS), 0, stream>>>(
      x, W0, b0, W1, b1, out, cnt, O0, H1);
}

// Round 2
// 3401.894 us; speedup vs baseline: 1.0329x; 1.0329x over previous
//
#include <hip/hip_runtime.h>

// Persistent pipelined 2-layer LSTM for MI355X (gfx950).
// R11: R9 topology (single polled line per lane) + last-arriver broadcast
//      (no master detect hop) + 4-deep pipelined consumer polls.
//  - 256 WGs x 512 threads; blocks 0..127 layer 0, 128..255 layer 1.
//  - waves: ntile = wave>>2 (batch 16-tile), r = wave&3:
//      r 0,1 -> h-waves (K-halves of the recurrent part, both M-tiles;
//               r1 runs the epilogue), r 2,3 -> x-waves (K-halves of x-part).
//  - window w: h-waves run step t=w-1; x-waves compute x-partials for step w
//    into LDS xbuf (double buffer) AFTER the mid sync -> hidden under the poll.
//  - per-LAYER barrier (R11): epilogue waves LDS-combine to ONE agent RMW on
//    stripe (lidx&15) (8 WGs/stripe). fetch_add RETURN drives aggregation:
//    stripe-finisher (old==e*8-1) RMWs a level-2 counter; level-2 finisher
//    (old==e*16-1) stores the 16 release replicas directly. No poller ever
//    touches stripe/lvl2 lines; every poll is a single replicated line:
//      lane 0  : own release[lidx&15] >= e
//      lane 17 : other layer's release[lidx&15] >= progEpoch (0 = skip)
//    polled with a 4-deep rotated load pipeline (detect at ~RT/4 granularity).
//  - h publish sc1 (write-through to LLC); consume plain-cached (write-once
//    slots + launch-boundary L2 invalidate => never stale). release=e implies
//    all publishes drained (RMW issued after vmcnt(0); release after RMW ret).
// Bounded sleep-free spins + abort flag: failure = fast reported absmax.

typedef unsigned short ushort_t;
typedef unsigned long long u64_t;
typedef __attribute__((ext_vector_type(8))) short short8;   // 8 bf16 MFMA operand
typedef __attribute__((ext_vector_type(4))) float f32x4;

#define NWG       256
#define NTHREADS  512
#define SEQ       512
#define HSLOT     32768        // 32*1024 elements per time slot
#define FULLSLOTS 513
#define LBASE     4096         // per-layer counter region, u32 units (16 KB)
#define LVL2OFF   1024         // level-2 counter (u32 offset within region)
#define RELOFF    2048         // release replicas at base+2048+i*32 (128B apart)
#define ABORT_U32 8128         // one global abort word
#define CNT_BYTES 32768
#define POLL_MAX  20000        // then abort -> fast wrong-answer, not a hang

__device__ __forceinline__ ushort_t f2bf(float f) {
  unsigned u = __builtin_bit_cast(unsigned, f);
  u += 0x7FFFu + ((u >> 16) & 1u);      // round-to-nearest-even
  return (ushort_t)(u >> 16);
}

__device__ __forceinline__ short8 pack_bf8(f32x4 a, f32x4 b) {
  short8 r;
  r[0] = (short)f2bf(a[0]); r[1] = (short)f2bf(a[1]);
  r[2] = (short)f2bf(a[2]); r[3] = (short)f2bf(a[3]);
  r[4] = (short)f2bf(b[0]); r[5] = (short)f2bf(b[1]);
  r[6] = (short)f2bf(b[2]); r[7] = (short)f2bf(b[3]);
  return r;
}

__device__ __forceinline__ float sigm(float x) { return 1.0f / (1.0f + __expf(-x)); }
__device__ __forceinline__ float fast_tanh(float x) {
  x = fminf(fmaxf(x, -15.f), 15.f);
  float e = __expf(-2.0f * x);
  return (1.0f - e) / (1.0f + e);
}

__device__ __forceinline__ unsigned aload(const unsigned* p) {
  return __hip_atomic_load(p, __ATOMIC_RELAXED, __HIP_MEMORY_SCOPE_AGENT);
}

// Per-layer barrier epoch (R11).
// Arrive: epilogue waves (1,5) lane0 LDS-combine; 2nd does agent fetch_add on
// stripe (lidx&15). Return value chains the aggregation (no master polling):
//   old==e*8-1  -> fetch_add(lvl2);  old==e*16-1 -> store 16 release replicas.
// Poll (wave 0): lane 0 own release, lane 17 other layer's release; 4-deep
// pipelined loads so detection granularity ~RT/4.
__device__ __forceinline__ void bar_epoch(unsigned* cntOwn, unsigned* relOther,
                                          unsigned* abortp, unsigned* hcount,
                                          unsigned e, int lidx,
                                          unsigned progEpoch) {
  const int wave = threadIdx.x >> 6;
  const int lane = threadIdx.x & 63;

  if (wave == 1 || wave == 5) {
    int dr = 0;
    if (lane == 0) {
      unsigned old = atomicAdd(hcount, 1u);          // LDS combine, monotonic
      dr = (int)(old & 1u);
    }
    dr = __shfl(dr, 0);
    int lastAll = 0;
    if (dr && lane == 0) {
      unsigned olds = __hip_atomic_fetch_add(cntOwn + (lidx & 15) * 64, 1u,
                              __ATOMIC_RELAXED, __HIP_MEMORY_SCOPE_AGENT);
      if (olds == e * 8u - 1u) {                     // stripe finisher
        unsigned oldl = __hip_atomic_fetch_add(cntOwn + LVL2OFF, 1u,
                              __ATOMIC_RELAXED, __HIP_MEMORY_SCOPE_AGENT);
        lastAll = (oldl == e * 16u - 1u);            // layer finisher
      }
    }
    lastAll = __shfl(lastAll, 0);
    if (lastAll && lane < 16)
      __hip_atomic_store(cntOwn + RELOFF + lane * 32, e,
                         __ATOMIC_RELAXED, __HIP_MEMORY_SCOPE_AGENT);
  }

  if (wave == 0) {
    const unsigned* addr = nullptr;
    unsigned tgt = 0;
    if (lane == 0) {
      addr = cntOwn + RELOFF + (lidx & 15) * 32;  tgt = e;
    } else if (lane == 17 && progEpoch) {
      addr = relOther + (lidx & 15) * 32;         tgt = progEpoch;
    }
    if (addr) {
      unsigned a0 = aload(addr), a1 = aload(addr);
      unsigned a2 = aload(addr), a3 = aload(addr);
      for (int it = 0;; ++it) {
        if (a0 >= tgt) break;
        if ((it & 63) == 63 && aload(abortp) != 0) break;
        if (it >= POLL_MAX) {
          __hip_atomic_store(abortp, 1u, __ATOMIC_RELAXED, __HIP_MEMORY_SCOPE_AGENT);
          break;
        }
        a0 = a1; a1 = a2; a2 = a3; a3 = aload(addr);
      }
    }
  }
  __syncthreads();   // window boundary
}

// One layer: 513 windows (w=0..512), barrier epoch e=w+2 after each.
//   window w: h-waves run step t=w-1 (w>=1); x-waves compute x-part of step
//   s=w (s<SEQ) into xbuf[s&1] AFTER the mid sync (hidden under the poll).
// MFMA 16x16x32: A row m: gate=m&3, unit=ub+mt*4+(m>>2).
// C/D: col = lane&15 (=batch), row = (lane>>4)*4 + reg -> reg = gate.
template<int KX, bool XFP32, bool ISL1>
__device__ __forceinline__ void run_layer(
    const void* xsrc, long x_step, long x_bstride,
    const ushort_t* __restrict__ hbuf, ushort_t* __restrict__ hbuf_w,
    const float* __restrict__ W, int ldw,
    const float* __restrict__ bias,
    float* __restrict__ out, int out_h_off, int out_c_off, int write_last,
    float* xbuf, float* red, unsigned* hcount,
    unsigned* cntOwn, unsigned* relOther, unsigned* abortp,
    int lidx, int ub)
{
  constexpr int XCH = (KX / 2) / 32;                // x chunks per x-wave
  const int lane  = threadIdx.x & 63;
  const int wave  = threadIdx.x >> 6;               // 0..7
  const int ntile = wave >> 2;                      // 0,1
  const int r     = wave & 3;                       // 0,1: h-waves; 2,3: x-waves
  const bool isH  = r < 2;
  const int sub   = r & 1;
  const int wrow  = lane & 15;
  const int koff  = (lane >> 4) * 8;                // frag k offset (elements)
  const int bb    = ntile * 16 + (lane & 15);       // batch

  // ---- pin weight fragments (bf16), 2 M-tiles per wave ----
  const int kbase = isH ? (KX + sub * 512) : ((r - 2) * (KX / 2));
  const int mych  = isH ? 16 : XCH;
  short8 wreg[2][16];
  #pragma unroll
  for (int mt = 0; mt < 2; ++mt) {
    const int grow = (wrow & 3) * 1024 + ub + mt * 4 + (wrow >> 2);
    const float* ws = W + (long)grow * ldw + kbase + koff;
    #pragma unroll
    for (int ch = 0; ch < 16; ++ch) {
      if (ch < mych) {
        f32x4 v0 = *(const f32x4*)(ws + ch * 32);
        f32x4 v1 = *(const f32x4*)(ws + ch * 32 + 4);
        wreg[mt][ch] = pack_bf8(v0, v1);
      }
    }
  }

  const int u0 = ub + (lane >> 4);
  float bI[2], bF[2], bG[2], bO[2], c[2] = {0.f, 0.f};
  #pragma unroll
  for (int mt = 0; mt < 2; ++mt) {
    const int u = u0 + mt * 4;
    bI[mt] = bias[u];        bF[mt] = bias[1024 + u];
    bG[mt] = bias[2048 + u]; bO[mt] = bias[3072 + u];
  }

  for (int w = 0; w <= SEQ; ++w) {
    const int t = w - 1;
    f32x4 acc[2] = {{0.f,0.f,0.f,0.f},{0.f,0.f,0.f,0.f}};

    if (isH && w >= 1) {
      // h K-half: 16x16B loads in one flight, 32 MFMAs (2 M-tiles)
      const ushort_t* bp = hbuf + (long)t * HSLOT + (long)bb * 1024 + sub * 512 + koff;
      short8 hv[16];
      #pragma unroll
      for (int ch = 0; ch < 16; ++ch) hv[ch] = *(const short8*)(bp + ch * 32);
      #pragma unroll
      for (int ch = 0; ch < 16; ++ch) {
        acc[0] = __builtin_amdgcn_mfma_f32_16x16x32_bf16(wreg[0][ch], hv[ch], acc[0], 0, 0, 0);
        acc[1] = __builtin_amdgcn_mfma_f32_16x16x32_bf16(wreg[1][ch], hv[ch], acc[1], 0, 0, 0);
      }
      if (sub == 0) {
        #pragma unroll
        for (int mt = 0; mt < 2; ++mt)
          *(f32x4*)&red[((ntile * 2 + mt) * 64 + lane) * 4] = acc[mt];
      }
    }

    __syncthreads();   // A: red ready; xbuf[t&1] from window t-1 already ready

    if (isH && sub == 1 && w >= 1) {
      // ---- epilogue (both M-tiles) ----
      u64_t pk[2]; float hh[2];
      #pragma unroll
      for (int mt = 0; mt < 2; ++mt) {
        f32x4 a = acc[mt];
        a += *(const f32x4*)&red[((ntile * 2 + mt) * 64 + lane) * 4];
        a += *(const f32x4*)&xbuf[(((((t & 1) * 2 + ntile) * 2 + 0) * 2 + mt) * 64 + lane) * 4];
        a += *(const f32x4*)&xbuf[(((((t & 1) * 2 + ntile) * 2 + 1) * 2 + mt) * 64 + lane) * 4];
        float pi = a[0] + bI[mt], pf = a[1] + bF[mt];
        float pg = a[2] + bG[mt], po = a[3] + bO[mt];
        float ig = sigm(pi), fg = sigm(pf), gg = fast_tanh(pg), og = sigm(po);
        c[mt] = fg * c[mt] + ig * gg;
        float h = og * fast_tanh(c[mt]);
        hh[mt] = h;
        unsigned v  = f2bf(h);
        unsigned v1 = __shfl((int)v, (lane & 15) + 16);
        unsigned v2 = __shfl((int)v, (lane & 15) + 32);
        unsigned v3 = __shfl((int)v, (lane & 15) + 48);
        pk[mt] = (u64_t)(v & 0xFFFFu) | ((u64_t)(v1 & 0xFFFFu) << 16)
               | ((u64_t)(v2 & 0xFFFFu) << 32) | ((u64_t)(v3 & 0xFFFFu) << 48);
      }
      if (t == SEQ - 1) {
        #pragma unroll
        for (int mt = 0; mt < 2; ++mt) {
          const int u = u0 + mt * 4;
          out[out_h_off + bb * 1024 + u] = hh[mt];
          out[out_c_off + bb * 1024 + u] = c[mt];
          if (write_last) out[bb * 1024 + u] = hh[mt];
        }
      }
      if (lane < 16) {
        u64_t* dst = (u64_t*)(hbuf_w + (long)(t + 1) * HSLOT + (long)bb * 1024 + ub);
        __hip_atomic_store(dst,     pk[0], __ATOMIC_RELAXED, __HIP_MEMORY_SCOPE_AGENT);
        __hip_atomic_store(dst + 1, pk[1], __ATOMIC_RELAXED, __HIP_MEMORY_SCOPE_AGENT);
      }
      asm volatile("s_waitcnt vmcnt(0)" ::: "memory");   // drain publish
    }

    if (!isH && w < SEQ) {
      // ---- x-prefetch for step s=w (off critical path, hidden under poll) ----
      const int s = w;
      f32x4 xa[2] = {{0.f,0.f,0.f,0.f},{0.f,0.f,0.f,0.f}};
      if constexpr (XFP32) {
        const float* bp = (const float*)xsrc + (long)s * x_step
                          + (long)bb * x_bstride + kbase + koff;
        f32x4 xv[2 * XCH];
        #pragma unroll
        for (int ch = 0; ch < XCH; ++ch) {
          xv[2*ch]   = *(const f32x4*)(bp + ch * 32);
          xv[2*ch+1] = *(const f32x4*)(bp + ch * 32 + 4);
        }
        #pragma unroll
        for (int ch = 0; ch < XCH; ++ch) {
          short8 bf = pack_bf8(xv[2*ch], xv[2*ch+1]);
          xa[0] = __builtin_amdgcn_mfma_f32_16x16x32_bf16(wreg[0][ch], bf, xa[0], 0, 0, 0);
          xa[1] = __builtin_amdgcn_mfma_f32_16x16x32_bf16(wreg[1][ch], bf, xa[1], 0, 0, 0);
        }
      } else {
        const ushort_t* bp = (const ushort_t*)xsrc + (long)s * x_step
                             + (long)bb * x_bstride + kbase + koff;
        short8 xv[16];
        #pragma unroll
        for (int ch = 0; ch < 16; ++ch) xv[ch] = *(const short8*)(bp + ch * 32);
        #pragma unroll
        for (int ch = 0; ch < 16; ++ch) {
          xa[0] = __builtin_amdgcn_mfma_f32_16x16x32_bf16(wreg[0][ch], xv[ch], xa[0], 0, 0, 0);
          xa[1] = __builtin_amdgcn_mfma_f32_16x16x32_bf16(wreg[1][ch], xv[ch], xa[1], 0, 0, 0);
        }
      }
      #pragma unroll
      for (int mt = 0; mt < 2; ++mt)
        *(f32x4*)&xbuf[(((((s & 1) * 2 + ntile) * 2 + (r - 2)) * 2 + mt) * 64 + lane) * 4] = xa[mt];
    }

    // barrier epoch e = w+2; gates window w+1 (needs O0 slot w+2 for L1 x)
    const unsigned e = (unsigned)(w + 2);
    const unsigned pt = (ISL1 && e <= 512u) ? (e + 2u) : 0u;
    bar_epoch(cntOwn, relOther, abortp, hcount, e, lidx, pt);
  }
}

__global__ __launch_bounds__(NTHREADS, 2)
void lstm_persistent(const float* __restrict__ x,  const float* __restrict__ W0,
                     const float* __restrict__ b0, const float* __restrict__ W1,
                     const float* __restrict__ b1, float* __restrict__ out,
                     unsigned* cnt, ushort_t* O0, ushort_t* H1)
{
  __shared__ float    xbuf[4096];   // [buf2][ntile2][xsub2][mt2][64][4] = 16 KB
  __shared__ float    red[1024];    // [ntile2][mt2][64][4] = 4 KB
  __shared__ unsigned hcount;
  const int  role = (int)(blockIdx.x >> 7);      // 0: layer0, 1: layer1
  const int  lidx = (int)(blockIdx.x & 127);
  const int  ub   = lidx * 8;
  unsigned* cntOwn  = cnt + role * LBASE;
  unsigned* relOther= cnt + (1 - role) * LBASE + RELOFF;
  unsigned* abortp  = cnt + ABORT_U32;

  if (threadIdx.x == 0) hcount = 0;

  // zero own slice of slot 0 (this WG's publish region), device-visible (sc1)
  ushort_t* hb = role ? H1 : O0;
  if (threadIdx.x < 128) {
    int b = threadIdx.x >> 2, p = threadIdx.x & 3;
    __hip_atomic_store((unsigned*)hb + (long)b * 512 + (ub >> 1) + p, 0u,
                       __ATOMIC_RELAXED, __HIP_MEMORY_SCOPE_AGENT);
  }
  asm volatile("s_waitcnt vmcnt(0)" ::: "memory");
  __syncthreads();

  // init barrier (epoch 1); gates window 0 (L1 window 0 x needs O0 slot 1 ->
  // L0 release >= 3 = e+2)
  bar_epoch(cntOwn, relOther, abortp, &hcount, 1u, lidx, role ? 3u : 0u);

  if (role == 0) {
    run_layer<512, true, false>(x, 512, 262144,
                                O0, O0, W0, 1536, b0,
                                out, 32768, 98304, 0,
                                xbuf, red, &hcount, cntOwn, relOther, abortp,
                                lidx, ub);
  } else {
    // L1 x source: O0 shifted by one slot (window-w x reads O0 slot w+1)
    run_layer<1024, false, true>((const void*)(O0 + HSLOT), HSLOT, 1024,
                                 H1, H1, W1, 2048, b1,
                                 out, 65536, 131072, 1,
                                 xbuf, red, &hcount, cntOwn, relOther, abortp,
                                 lidx, ub);
  }
}

extern "C" void kernel_launch(void* const* d_in, const int* in_sizes, int n_in,
                              void* d_out, int out_size, void* d_ws, size_t ws_size,
                              hipStream_t stream) {
  (void)in_sizes; (void)n_in; (void)out_size;

  const float* x  = (const float*)d_in[0];
  const float* W0 = (const float*)d_in[1];
  const float* b0 = (const float*)d_in[2];
  const float* W1 = (const float*)d_in[3];
  const float* b1 = (const float*)d_in[4];
  float* out = (float*)d_out;

  // workspace:
  //   [0, 32K)            2 per-layer counter regions:
  //                         stripes i*64, lvl2 at 1024, release at 2048+i*32
  //                       + abort word at 8128
  //   [32K, +513*64KB)    O0: layer-0 h slots (write-once)
  //   [.., +513*64KB)     H1: layer-1 h slots (write-once)
  const size_t hb_bytes = (size_t)FULLSLOTS * HSLOT * sizeof(ushort_t);
  const size_t need     = CNT_BYTES + 2 * hb_bytes;
  if (ws_size < need) return;  // wrong answer -> absmax signal, not a hang

  unsigned* cnt = (unsigned*)d_ws;
  ushort_t* O0  = (ushort_t*)((char*)d_ws + CNT_BYTES);
  ushort_t* H1  = O0 + (size_t)FULLSLOTS * HSLOT;

  hipMemsetAsync(d_ws, 0, CNT_BYTES, stream);

  lstm_persistent<<<dim3(NWG), dim3(NTHREADS), 0, stream>>>(
      x, W0, b0, W1, b1, out, cnt, O0, H1);
}

// Round 3
// 2354.744 us; speedup vs baseline: 1.4922x; 1.4447x over previous
//
#include <hip/hip_runtime.h>

// Persistent pipelined 2-layer LSTM for MI355X (gfx950).
// R12: DATAFLOW — the global flag barrier is DELETED. Consumers poll the h
// data itself via a sentinel encoding; producers publish fire-and-forget.
//  - 256 WGs x 512 threads; blocks 0..127 layer 0, 128..255 layer 1.
//  - waves: ntile = wave>>2 (batch 16-tile), r = wave&3:
//      r 0,1 -> h-waves (K-halves of recurrent part; r1 runs the epilogue),
//      r 2,3 -> x-waves (K-halves of the x-part, into LDS xbuf dbuf).
//  - slot layout (TRANSPOSED): [producer p=0..127][batch b=0..31] x 16B
//    granule = 8 h-columns (p*8..p*8+7) of one batch, written by exactly ONE
//    producer 16B store-pair. Consumer MFMA B-frag == one granule:
//    p = sub*64 + (lane>>4) + ch*4, addr = slot + (p*32+bb)*16, ch-stride 2KB.
//  - sentinel: host pre-fills slots 1..512 with 0xFF (dword 0xFFFFFFFF = two
//    bf16 -NaNs, unreachable for published h = sigm*tanh via f2bf). Slot 0 is
//    zero-filled (h0 = 0, valid). Validity checked PER DWORD (max4 == ~0u),
//    so store tearing at 8B/4B granularity is safe by construction.
//  - consumer poll: issue 16 global_load_dwordx4, one vmcnt(0) wait,
//    sched_barrier, check, retry. Retries use sc0 sc1 (bypass stale L1/L2 ->
//    LLC). h-waves poll coherent-first (they arrive early); L1 x-waves poll
//    plain-first (they run ~2 windows late; first L2 miss fills VALID lines
//    and XCD-mates share them — valid-once => final value, so always correct).
//  - producer: 2 agent u64 stores per lane<16, NO drain/arrive/release.
//  - no deadlock: L0 waits only on L0 slots, L1 on L0/L1; slots write-once.
// Bounded retries + abort flag: failure = fast wrong answer, never a hang.

typedef unsigned short ushort_t;
typedef unsigned long long u64_t;
typedef __attribute__((ext_vector_type(8))) short short8;   // 8 bf16 MFMA operand
typedef __attribute__((ext_vector_type(4))) float f32x4;
typedef __attribute__((ext_vector_type(4))) unsigned uint4v;

#define NWG       256
#define NTHREADS  512
#define SEQ       512
#define HSLOT     32768        // 32*1024 elements per time slot (64 KB)
#define FULLSLOTS 513
#define ABORT_U32 8128         // one global abort word (u32 index in cnt)
#define CNT_BYTES 32768
#define POLL_MAX  6000         // retries (~RT each) then abort -> fast fail

__device__ __forceinline__ ushort_t f2bf(float f) {
  unsigned u = __builtin_bit_cast(unsigned, f);
  u += 0x7FFFu + ((u >> 16) & 1u);      // round-to-nearest-even
  return (ushort_t)(u >> 16);
}

__device__ __forceinline__ short8 pack_bf8(f32x4 a, f32x4 b) {
  short8 r;
  r[0] = (short)f2bf(a[0]); r[1] = (short)f2bf(a[1]);
  r[2] = (short)f2bf(a[2]); r[3] = (short)f2bf(a[3]);
  r[4] = (short)f2bf(b[0]); r[5] = (short)f2bf(b[1]);
  r[6] = (short)f2bf(b[2]); r[7] = (short)f2bf(b[3]);
  return r;
}

__device__ __forceinline__ float sigm(float x) { return 1.0f / (1.0f + __expf(-x)); }
__device__ __forceinline__ float fast_tanh(float x) {
  x = fminf(fmaxf(x, -15.f), 15.f);
  float e = __expf(-2.0f * x);
  return (1.0f - e) / (1.0f + e);
}

__device__ __forceinline__ unsigned aload(const unsigned* p) {
  return __hip_atomic_load(p, __ATOMIC_RELAXED, __HIP_MEMORY_SCOPE_AGENT);
}

// Issue 16 granule loads (ch-stride 2 KB), single vmcnt(0), fence scheduling.
// COH: sc0 sc1 -> bypass L1/L2, service at LLC (needed for retry freshness).
template<bool COH>
__device__ __forceinline__ void load16g(f32x4* hv, const char* base) {
#pragma unroll
  for (int ch = 0; ch < 16; ++ch) {
    const char* a = base + (long)ch * 2048;
    if constexpr (COH)
      asm volatile("global_load_dwordx4 %0, %1, off sc0 sc1"
                   : "=v"(hv[ch]) : "v"(a));
    else
      asm volatile("global_load_dwordx4 %0, %1, off"
                   : "=v"(hv[ch]) : "v"(a));
  }
  asm volatile("s_waitcnt vmcnt(0)" ::: "memory");
  __builtin_amdgcn_sched_barrier(0);    // rule #18: pin uses after the wait
}

// Per-dword sentinel check over 16 granules: bad iff any dword == 0xFFFFFFFF.
__device__ __forceinline__ int bad16(const f32x4* hv) {
  int bad = 0;
#pragma unroll
  for (int ch = 0; ch < 16; ++ch) {
    uint4v d = __builtin_bit_cast(uint4v, hv[ch]);
    unsigned m0 = d[0] > d[1] ? d[0] : d[1];
    unsigned m1 = d[2] > d[3] ? d[2] : d[3];
    unsigned m  = m0 > m1 ? m0 : m1;       // v_max3 + v_max
    bad |= (int)(m == 0xFFFFFFFFu);
  }
  return bad;
}

// Poll one wave's 16 granules until all valid. FIRSTCOH: first attempt
// coherent (early consumers) vs plain-cached (late consumers; lets L2 share
// valid fills across the XCD — correct since granules are write-once).
template<bool FIRSTCOH>
__device__ __forceinline__ void poll16(f32x4* hv, const char* base,
                                       unsigned* abortp) {
  load16g<FIRSTCOH>(hv, base);
  if (!__any(bad16(hv))) return;
  for (int it = 0;; ++it) {
    load16g<true>(hv, base);
    if (!__any(bad16(hv))) return;
    if ((it & 63) == 63 && aload(abortp) != 0) return;
    if (it >= POLL_MAX) {
      __hip_atomic_store(abortp, 1u, __ATOMIC_RELAXED, __HIP_MEMORY_SCOPE_AGENT);
      return;
    }
    if (it > 8) __builtin_amdgcn_s_sleep(2);   // ~128 cy backoff
  }
}

// One layer: 513 windows (w=0..512).
//   window w: h-waves run step t=w-1 (w>=1); x-waves compute x-part of step
//   s=w (s<SEQ) into xbuf[s&1] AFTER the mid sync.
// MFMA 16x16x32: A row m: gate=m&3, unit=ub+mt*4+(m>>2).
// C/D: col = lane&15 (=batch), row = (lane>>4)*4 + reg -> reg = gate.
template<int KX, bool XFP32, bool ISL1>
__device__ __forceinline__ void run_layer(
    const void* xsrc, long x_step, long x_bstride,
    const ushort_t* __restrict__ hbuf, ushort_t* __restrict__ hbuf_w,
    const float* __restrict__ W, int ldw,
    const float* __restrict__ bias,
    float* __restrict__ out, int out_h_off, int out_c_off, int write_last,
    float* xbuf, float* red, unsigned* abortp, int ub)
{
  constexpr int XCH = (KX / 2) / 32;                // x chunks per x-wave
  const int lane  = threadIdx.x & 63;
  const int wave  = threadIdx.x >> 6;               // 0..7
  const int ntile = wave >> 2;                      // 0,1
  const int r     = wave & 3;                       // 0,1: h-waves; 2,3: x-waves
  const bool isH  = r < 2;
  const int sub   = r & 1;
  const int wrow  = lane & 15;
  const int kg    = lane >> 4;                      // frag k-group (0..3)
  const int koff  = kg * 8;                         // frag k offset (elements)
  const int bb    = ntile * 16 + (lane & 15);       // batch

  // ---- pin weight fragments (bf16), 2 M-tiles per wave ----
  const int kbase = isH ? (KX + sub * 512) : ((r - 2) * (KX / 2));
  const int mych  = isH ? 16 : XCH;
  short8 wreg[2][16];
  #pragma unroll
  for (int mt = 0; mt < 2; ++mt) {
    const int grow = (wrow & 3) * 1024 + ub + mt * 4 + (wrow >> 2);
    const float* ws = W + (long)grow * ldw + kbase + koff;
    #pragma unroll
    for (int ch = 0; ch < 16; ++ch) {
      if (ch < mych) {
        f32x4 v0 = *(const f32x4*)(ws + ch * 32);
        f32x4 v1 = *(const f32x4*)(ws + ch * 32 + 4);
        wreg[mt][ch] = pack_bf8(v0, v1);
      }
    }
  }

  const int u0 = ub + kg;
  float bI[2], bF[2], bG[2], bO[2], c[2] = {0.f, 0.f};
  #pragma unroll
  for (int mt = 0; mt < 2; ++mt) {
    const int u = u0 + mt * 4;
    bI[mt] = bias[u];        bF[mt] = bias[1024 + u];
    bG[mt] = bias[2048 + u]; bO[mt] = bias[3072 + u];
  }

  for (int w = 0; w <= SEQ; ++w) {
    const int t = w - 1;
    f32x4 acc[2] = {{0.f,0.f,0.f,0.f},{0.f,0.f,0.f,0.f}};

    if (isH && w >= 1) {
      // h K-half: poll 16 granules (one per MFMA), then 32 MFMAs (2 M-tiles)
      const char* gb = (const char*)hbuf + (long)t * (HSLOT * 2)
                     + (long)(((sub * 64 + kg) * 32 + bb) * 16);
      f32x4 hv[16];
      poll16<true>(hv, gb, abortp);
      #pragma unroll
      for (int ch = 0; ch < 16; ++ch) {
        short8 b = __builtin_bit_cast(short8, hv[ch]);
        acc[0] = __builtin_amdgcn_mfma_f32_16x16x32_bf16(wreg[0][ch], b, acc[0], 0, 0, 0);
        acc[1] = __builtin_amdgcn_mfma_f32_16x16x32_bf16(wreg[1][ch], b, acc[1], 0, 0, 0);
      }
      if (sub == 0) {
        #pragma unroll
        for (int mt = 0; mt < 2; ++mt)
          *(f32x4*)&red[((ntile * 2 + mt) * 64 + lane) * 4] = acc[mt];
      }
    }

    __syncthreads();   // A: red ready; xbuf[t&1] from window t-1 already ready

    if (isH && sub == 1 && w >= 1) {
      // ---- epilogue (both M-tiles) ----
      u64_t pk[2]; float hh[2];
      #pragma unroll
      for (int mt = 0; mt < 2; ++mt) {
        f32x4 a = acc[mt];
        a += *(const f32x4*)&red[((ntile * 2 + mt) * 64 + lane) * 4];
        a += *(const f32x4*)&xbuf[(((((t & 1) * 2 + ntile) * 2 + 0) * 2 + mt) * 64 + lane) * 4];
        a += *(const f32x4*)&xbuf[(((((t & 1) * 2 + ntile) * 2 + 1) * 2 + mt) * 64 + lane) * 4];
        float pi = a[0] + bI[mt], pf = a[1] + bF[mt];
        float pg = a[2] + bG[mt], po = a[3] + bO[mt];
        float ig = sigm(pi), fg = sigm(pf), gg = fast_tanh(pg), og = sigm(po);
        c[mt] = fg * c[mt] + ig * gg;
        float h = og * fast_tanh(c[mt]);
        hh[mt] = h;
        unsigned v  = f2bf(h);
        unsigned v1 = __shfl((int)v, (lane & 15) + 16);
        unsigned v2 = __shfl((int)v, (lane & 15) + 32);
        unsigned v3 = __shfl((int)v, (lane & 15) + 48);
        pk[mt] = (u64_t)(v & 0xFFFFu) | ((u64_t)(v1 & 0xFFFFu) << 16)
               | ((u64_t)(v2 & 0xFFFFu) << 32) | ((u64_t)(v3 & 0xFFFFu) << 48);
      }
      if (t == SEQ - 1) {
        #pragma unroll
        for (int mt = 0; mt < 2; ++mt) {
          const int u = u0 + mt * 4;
          out[out_h_off + bb * 1024 + u] = hh[mt];
          out[out_c_off + bb * 1024 + u] = c[mt];
          if (write_last) out[bb * 1024 + u] = hh[mt];
        }
      }
      if (lane < 16) {
        // transposed granule: (p = ub>>3, bb) -> 16B, fire-and-forget
        u64_t* dst = (u64_t*)((char*)hbuf_w + (long)(t + 1) * (HSLOT * 2)
                              + (long)((((ub >> 3) * 32 + bb)) * 16));
        __hip_atomic_store(dst,     pk[0], __ATOMIC_RELAXED, __HIP_MEMORY_SCOPE_AGENT);
        __hip_atomic_store(dst + 1, pk[1], __ATOMIC_RELAXED, __HIP_MEMORY_SCOPE_AGENT);
      }
      // no drain: consumers self-synchronize on the data
    }

    if (!isH && w < SEQ) {
      // ---- x-part for step s=w (hidden under h-critical path) ----
      const int s = w;
      f32x4 xa[2] = {{0.f,0.f,0.f,0.f},{0.f,0.f,0.f,0.f}};
      if constexpr (XFP32) {
        const float* bp = (const float*)xsrc + (long)s * x_step
                          + (long)bb * x_bstride + kbase + koff;
        f32x4 xv[2 * XCH];
        #pragma unroll
        for (int ch = 0; ch < XCH; ++ch) {
          xv[2*ch]   = *(const f32x4*)(bp + ch * 32);
          xv[2*ch+1] = *(const f32x4*)(bp + ch * 32 + 4);
        }
        #pragma unroll
        for (int ch = 0; ch < XCH; ++ch) {
          short8 bf = pack_bf8(xv[2*ch], xv[2*ch+1]);
          xa[0] = __builtin_amdgcn_mfma_f32_16x16x32_bf16(wreg[0][ch], bf, xa[0], 0, 0, 0);
          xa[1] = __builtin_amdgcn_mfma_f32_16x16x32_bf16(wreg[1][ch], bf, xa[1], 0, 0, 0);
        }
      } else {
        // L1 x = O0 slot s+1 (xsrc pre-shifted by one slot): sentinel-polled,
        // plain-first (late consumer -> valid L2 fills shared across XCD).
        const char* gb = (const char*)xsrc + (long)s * (HSLOT * 2)
                       + (long)((((r - 2) * 64 + kg) * 32 + bb) * 16);
        f32x4 xv[16];
        poll16<false>(xv, gb, abortp);
        #pragma unroll
        for (int ch = 0; ch < 16; ++ch) {
          short8 b = __builtin_bit_cast(short8, xv[ch]);
          xa[0] = __builtin_amdgcn_mfma_f32_16x16x32_bf16(wreg[0][ch], b, xa[0], 0, 0, 0);
          xa[1] = __builtin_amdgcn_mfma_f32_16x16x32_bf16(wreg[1][ch], b, xa[1], 0, 0, 0);
        }
      }
      #pragma unroll
      for (int mt = 0; mt < 2; ++mt)
        *(f32x4*)&xbuf[(((((s & 1) * 2 + ntile) * 2 + (r - 2)) * 2 + mt) * 64 + lane) * 4] = xa[mt];
    }

    __syncthreads();   // window boundary (xbuf/red reuse)
  }
}

__global__ __launch_bounds__(NTHREADS, 2)
void lstm_persistent(const float* __restrict__ x,  const float* __restrict__ W0,
                     const float* __restrict__ b0, const float* __restrict__ W1,
                     const float* __restrict__ b1, float* __restrict__ out,
                     unsigned* cnt, ushort_t* O0, ushort_t* H1)
{
  __shared__ float xbuf[4096];   // [buf2][ntile2][xsub2][mt2][64][4] = 16 KB
  __shared__ float red[1024];    // [ntile2][mt2][64][4] = 4 KB
  const int role = (int)(blockIdx.x >> 7);      // 0: layer0, 1: layer1
  const int ub   = (int)(blockIdx.x & 127) * 8;
  unsigned* abortp = cnt + ABORT_U32;

  if (role == 0) {
    run_layer<512, true, false>(x, 512, 262144,
                                O0, O0, W0, 1536, b0,
                                out, 32768, 98304, 0,
                                xbuf, red, abortp, ub);
  } else {
    // L1 x source: O0 shifted by one slot (window-w x reads O0 slot w+1)
    run_layer<1024, false, true>((const void*)(O0 + HSLOT), HSLOT, 1024,
                                 H1, H1, W1, 2048, b1,
                                 out, 65536, 131072, 1,
                                 xbuf, red, abortp, ub);
  }
}

extern "C" void kernel_launch(void* const* d_in, const int* in_sizes, int n_in,
                              void* d_out, int out_size, void* d_ws, size_t ws_size,
                              hipStream_t stream) {
  (void)in_sizes; (void)n_in; (void)out_size;

  const float* x  = (const float*)d_in[0];
  const float* W0 = (const float*)d_in[1];
  const float* b0 = (const float*)d_in[2];
  const float* W1 = (const float*)d_in[3];
  const float* b1 = (const float*)d_in[4];
  float* out = (float*)d_out;

  // workspace:
  //   [0, 32K)            abort word region
  //   [32K, +513*64KB)    O0: layer-0 h slots (write-once, transposed layout)
  //   [.., +513*64KB)     H1: layer-1 h slots
  const size_t hb_bytes = (size_t)FULLSLOTS * HSLOT * sizeof(ushort_t);
  const size_t need     = CNT_BYTES + 2 * hb_bytes;
  if (ws_size < need) return;  // wrong answer -> absmax signal, not a hang

  unsigned* cnt = (unsigned*)d_ws;
  ushort_t* O0  = (ushort_t*)((char*)d_ws + CNT_BYTES);
  ushort_t* H1  = O0 + (size_t)FULLSLOTS * HSLOT;

  hipMemsetAsync(cnt, 0, CNT_BYTES, stream);
  // slot 0 = zeros (h0 = 0, VALID); slots 1..512 = 0xFF sentinel
  hipMemsetAsync(O0, 0x00, (size_t)HSLOT * 2, stream);
  hipMemsetAsync(O0 + HSLOT, 0xFF, (size_t)(FULLSLOTS - 1) * HSLOT * 2, stream);
  hipMemsetAsync(H1, 0x00, (size_t)HSLOT * 2, stream);
  hipMemsetAsync(H1 + HSLOT, 0xFF, (size_t)(FULLSLOTS - 1) * HSLOT * 2, stream);

  lstm_persistent<<<dim3(NWG), dim3(NTHREADS), 0, stream>>>(
      x, W0, b0, W1, b1, out, cnt, O0, H1);
}